// Round 2
// baseline (317.810 us; speedup 1.0000x reference)
//
#include <hip/hip_runtime.h>
#include <math.h>

#define H 1024
#define S 32768
#define NBLK 512            // 2 blocks/CU x 256 CUs -> entire grid co-resident
#define RPW 16              // rows per wave (4 waves/block -> 64 rows/block)

// ws layout (floats):
//   [0, 16384)        part[p][h]   p<16, h<1024   (W^T@hidden d-partials)
//   [16384, 17408)    v[H]         final matvec
//   [17408, 17920)    pm[NBLK]     per-block softmax max
//   [17920, 18432)    ps[NBLK]     per-block softmax sumexp
//   [18432, ...)      counters (int): [0]=parts done, [1]=v ready, [2]=blocks done
#define WS_PART 0
#define WS_V    16384
#define WS_PM   17408
#define WS_PS   17920
#define WS_CTR  18432

__device__ __forceinline__ float dot16(const float4 e0, const float4 e1,
                                       const float4 e2, const float4 e3,
                                       const float4 vf[4]) {
    float s0 = e0.x * vf[0].x + e0.y * vf[0].y + e0.z * vf[0].z + e0.w * vf[0].w;
    float s1 = e1.x * vf[1].x + e1.y * vf[1].y + e1.z * vf[1].z + e1.w * vf[1].w;
    float s2 = e2.x * vf[2].x + e2.y * vf[2].y + e2.z * vf[2].z + e2.w * vf[2].w;
    float s3 = e3.x * vf[3].x + e3.y * vf[3].y + e3.z * vf[3].z + e3.w * vf[3].w;
    return (s0 + s1) + (s2 + s3);
}

// Bounded spin: fails loud (wrong result) instead of hanging if counters
// were somehow not zeroed. Normal wait is ~1e2-1e4 polls.
__device__ __forceinline__ void spin_until_ge(int* p, int target) {
    int guard = 0;
    while (__hip_atomic_load(p, __ATOMIC_RELAXED, __HIP_MEMORY_SCOPE_AGENT) < target) {
        __builtin_amdgcn_s_sleep(2);
        if (++guard > 20000000) break;
    }
}

__global__ __launch_bounds__(256, 2) void attn_fused(const float* __restrict__ hidden,
                                                     const float* __restrict__ enc,
                                                     const float* __restrict__ W,
                                                     float* __restrict__ ws,
                                                     float* __restrict__ out) {
    float* part = ws + WS_PART;
    float* v    = ws + WS_V;
    float* pm   = ws + WS_PM;
    float* ps   = ws + WS_PS;
    int*   ctr  = (int*)(ws + WS_CTR);

    const int tid  = threadIdx.x;
    const int lane = tid & 63;
    const int wv   = tid >> 6;
    const int blk  = blockIdx.x;

    __shared__ float red[4][64];
    __shared__ float sm[4], ss[4];
    __shared__ float outsh[64];

    // ---- Phase 0: blocks 0..255 compute W^T@hidden d-partials ----
    if (blk < 256) {
        const int dg = tid >> 6;                    // d sub-chunk 0..3
        const int h  = (blk & 15) * 64 + lane;
        const int d0 = (blk >> 4) * 64 + dg * 16;
        float acc = 0.f;
#pragma unroll
        for (int i = 0; i < 16; ++i)
            acc += W[(size_t)(d0 + i) * H + h] * hidden[d0 + i];
        red[dg][lane] = acc;
        __syncthreads();
        if (tid < 64)
            part[(blk >> 4) * H + (blk & 15) * 64 + tid] =
                red[0][tid] + red[1][tid] + red[2][tid] + red[3][tid];
        __syncthreads();                            // drain part stores (vmcnt0 before barrier)
        if (tid == 0)
            __hip_atomic_fetch_add(&ctr[0], 1, __ATOMIC_RELEASE, __HIP_MEMORY_SCOPE_AGENT);
    }

    // ---- Phase 0b: block 0 reduces the 16 partials into v ----
    if (blk == 0) {
        if (tid == 0) spin_until_ge(&ctr[0], 256);
        __syncthreads();
        __threadfence();                            // acquire: see remote part stores
        const float4* p4 = (const float4*)part;
        float4 a4 = p4[tid];
#pragma unroll
        for (int p = 1; p < 16; ++p) {
            const float4 w4 = p4[p * 256 + tid];
            a4.x += w4.x; a4.y += w4.y; a4.z += w4.z; a4.w += w4.w;
        }
        ((float4*)v)[tid] = a4;
        __syncthreads();                            // drain v stores
        if (tid == 0)
            __hip_atomic_store(&ctr[1], 1, __ATOMIC_RELEASE, __HIP_MEMORY_SCOPE_AGENT);
    }

    // ---- Phase 1: scores. Prefetch 2 enc rows BEFORE waiting on v so the
    // dominant HBM stream starts immediately and hides the v critical path.
    const int gw = blk * 4 + wv;                    // global wave id, owns rows gw*16..+16
    const float4* e4 = (const float4*)enc + (size_t)gw * (RPW * (H / 4));

    float4 p00 = e4[lane],       p01 = e4[lane + 64],
           p02 = e4[lane + 128], p03 = e4[lane + 192];
    float4 p10 = e4[256 + lane],       p11 = e4[256 + lane + 64],
           p12 = e4[256 + lane + 128], p13 = e4[256 + lane + 192];

    if (tid == 0) spin_until_ge(&ctr[1], 1);
    __syncthreads();
    __threadfence();                                // acquire: see v

    const float4* v4 = (const float4*)v;
    float4 vf[4];
#pragma unroll
    for (int k = 0; k < 4; ++k) vf[k] = v4[lane + 64 * k];

    float a[RPW];
    a[0] = dot16(p00, p01, p02, p03, vf);
    a[1] = dot16(p10, p11, p12, p13, vf);
#pragma unroll
    for (int it = 2; it < RPW; ++it) {
        const float4* r = e4 + it * 256;
        a[it] = dot16(r[lane], r[lane + 64], r[lane + 128], r[lane + 192], vf);
    }

    // butterfly each row; full row-sum lands in ALL lanes (kept for phase 2)
#pragma unroll
    for (int it = 0; it < RPW; ++it) {
#pragma unroll
        for (int off = 32; off > 0; off >>= 1)
            a[it] += __shfl_xor(a[it], off, 64);
    }

    // deferred wave softmax partial: fmax tree + independent exps
    float mw = a[0];
#pragma unroll
    for (int it = 1; it < RPW; ++it) mw = fmaxf(mw, a[it]);
    float sw = 0.f;
#pragma unroll
    for (int it = 0; it < RPW; ++it) sw += __expf(a[it] - mw);

    if (lane == 0) { sm[wv] = mw; ss[wv] = sw; }
    __syncthreads();
    if (tid == 0) {
        float m = sm[0], s = ss[0];
#pragma unroll
        for (int i = 1; i < 4; ++i) {
            const float nm = fmaxf(m, sm[i]);
            s = s * __expf(m - nm) + ss[i] * __expf(sm[i] - nm);
            m = nm;
        }
        pm[blk] = m; ps[blk] = s;
        __hip_atomic_fetch_add(&ctr[2], 1, __ATOMIC_RELEASE, __HIP_MEMORY_SCOPE_AGENT);
    }

    // ---- Phase 2: every block combines the 512 (m,s) pairs, normalizes its
    // own 64 rows straight from registers (no scores array, no extra kernel).
    if (tid == 0) spin_until_ge(&ctr[2], NBLK);
    __syncthreads();
    __threadfence();                                // acquire: see all pm/ps

    float m = -INFINITY, s = 0.f;
#pragma unroll
    for (int i = 0; i < 2; ++i) {
        const float om = pm[tid + i * 256], os = ps[tid + i * 256];
        const float nm = fmaxf(m, om);
        s = s * __expf(m - nm) + os * __expf(om - nm);
        m = nm;
    }
#pragma unroll
    for (int off = 32; off > 0; off >>= 1) {
        const float om = __shfl_xor(m, off, 64);
        const float os = __shfl_xor(s, off, 64);
        const float nm = fmaxf(m, om);
        s = s * __expf(m - nm) + os * __expf(om - nm);
        m = nm;
    }
    __syncthreads();                                // sm/ss reuse is safe after spin barrier
    if (lane == 0) { sm[wv] = m; ss[wv] = s; }
    __syncthreads();
    float M = sm[0], Ssum = ss[0];
#pragma unroll
    for (int i = 1; i < 4; ++i) {
        const float nm = fmaxf(M, sm[i]);
        Ssum = Ssum * __expf(M - nm) + ss[i] * __expf(sm[i] - nm);
        M = nm;
    }
    const float rs = 1.0f / Ssum;

    if (lane == 0) {
#pragma unroll
        for (int it = 0; it < RPW; ++it)
            outsh[wv * RPW + it] = __expf(a[it] - M) * rs;
    }
    __syncthreads();
    if (tid < 64) out[blk * 64 + tid] = outsh[tid];  // block owns rows blk*64..+64
}

extern "C" void kernel_launch(void* const* d_in, const int* in_sizes, int n_in,
                              void* d_out, int out_size, void* d_ws, size_t ws_size,
                              hipStream_t stream) {
    const float* hidden = (const float*)d_in[0];   // [H]
    const float* enc    = (const float*)d_in[1];   // [S, H]
    const float* W      = (const float*)d_in[2];   // [H, H]
    // d_in[3] = b — unused: b·hidden is a uniform softmax shift (cancels exactly).
    float* out = (float*)d_out;                    // [S] fp32
    float* ws  = (float*)d_ws;

    hipMemsetAsync((void*)(ws + WS_CTR), 0, 256, stream);   // zero spin counters
    attn_fused<<<NBLK, 256, 0, stream>>>(hidden, enc, W, ws, out);
}

// Round 3
// 204.102 us; speedup vs baseline: 1.5571x; 1.5571x over previous
//
#include <hip/hip_runtime.h>
#include <math.h>

#define H 1024
#define S 32768
#define NPART 16          // d-partials for the W^T @ hidden matvec
#define RPW 4             // rows per wave in K2 (low VGPR -> high occupancy)
#define NB2 2048          // K2 blocks: S / (4 waves * RPW)

// ws layout (floats):
//   [0, 16384)        part[p][h]   p<16, h<1024
//   [16384, 17408)    v[H]
//   [17408, 19456)    pm[NB2]      per-block softmax max
//   [19456, 21504)    ps[NB2]      per-block softmax sumexp
//   [21504, 54272)    scores[S]
#define WS_PART   0
#define WS_V      16384
#define WS_PM     17408
#define WS_PS     19456
#define WS_SCORES 21504

// ---------------------------------------------------------------------------
// K1: part[by][h] = sum_{d in by-chunk of 64} W[d][h] * hidden[d]
// grid (16,16), block 256. 256 blocks -> one per CU, 16 KB each.
// ---------------------------------------------------------------------------
__global__ __launch_bounds__(256) void matvec_partial(const float* __restrict__ W,
                                                      const float* __restrict__ hidden,
                                                      float* __restrict__ ws) {
    float* part = ws + WS_PART;
    const int t  = threadIdx.x;
    const int l  = t & 63;
    const int dg = t >> 6;
    const int h  = blockIdx.x * 64 + l;
    const int d0 = blockIdx.y * 64 + dg * 16;

    float acc = 0.f;
#pragma unroll
    for (int i = 0; i < 16; ++i)
        acc += W[(size_t)(d0 + i) * H + h] * hidden[d0 + i];

    __shared__ float red[4][64];
    red[dg][l] = acc;
    __syncthreads();
    if (t < 64)
        part[blockIdx.y * H + blockIdx.x * 64 + l] =
            red[0][l] + red[1][l] + red[2][l] + red[3][l];
}

// ---------------------------------------------------------------------------
// K1b: v[h] = sum_p part[p][h]. All 16 loads issued up front (no dependent
// chain across cross-XCD L2/L3 hits), then pairwise tree sum.
// grid 4 x 64 threads; thread owns one float4 column.
// ---------------------------------------------------------------------------
__device__ __forceinline__ float4 add4(float4 a, float4 b) {
    return make_float4(a.x + b.x, a.y + b.y, a.z + b.z, a.w + b.w);
}

__global__ __launch_bounds__(64) void reduce_v(float* __restrict__ ws) {
    const float* part = ws + WS_PART;
    float* v = ws + WS_V;
    const int i = blockIdx.x * 64 + threadIdx.x;   // float4 index < 256
    const float4* p4 = (const float4*)part;

    float4 t[NPART];
#pragma unroll
    for (int p = 0; p < NPART; ++p) t[p] = p4[p * (H / 4) + i];   // 16 independent loads
#pragma unroll
    for (int p = 0; p < 8; ++p) t[p] = add4(t[p], t[p + 8]);
#pragma unroll
    for (int p = 0; p < 4; ++p) t[p] = add4(t[p], t[p + 4]);
    t[0] = add4(add4(t[0], t[2]), add4(t[1], t[3]));
    ((float4*)v)[i] = t[0];
}

// ---------------------------------------------------------------------------
// K2: scores + per-block softmax partials. 2048 blocks x 256 threads,
// 4 rows/wave -> low register pressure, high occupancy, deep load pipeline.
// No LDS staging, no mid-kernel syncs; v comes from L2 (4 KB, broadcast-hot).
// ---------------------------------------------------------------------------
__device__ __forceinline__ float dot16(const float4 e0, const float4 e1,
                                       const float4 e2, const float4 e3,
                                       const float4 vf[4]) {
    float s0 = e0.x * vf[0].x + e0.y * vf[0].y + e0.z * vf[0].z + e0.w * vf[0].w;
    float s1 = e1.x * vf[1].x + e1.y * vf[1].y + e1.z * vf[1].z + e1.w * vf[1].w;
    float s2 = e2.x * vf[2].x + e2.y * vf[2].y + e2.z * vf[2].z + e2.w * vf[2].w;
    float s3 = e3.x * vf[3].x + e3.y * vf[3].y + e3.z * vf[3].z + e3.w * vf[3].w;
    return (s0 + s1) + (s2 + s3);
}

__global__ __launch_bounds__(256) void scores_partial(const float* __restrict__ enc,
                                                      float* __restrict__ ws) {
    float* scores = ws + WS_SCORES;
    float* pm     = ws + WS_PM;
    float* ps     = ws + WS_PS;
    const float* v = ws + WS_V;

    const int tid  = threadIdx.x;
    const int lane = tid & 63;
    const int wv   = tid >> 6;
    const int blk  = blockIdx.x;
    const int gw   = blk * 4 + wv;                 // global wave id
    const size_t row0 = (size_t)gw * RPW;

    const float4* v4 = (const float4*)v;
    float4 vf[4];
#pragma unroll
    for (int k = 0; k < 4; ++k) vf[k] = v4[lane + 64 * k];

    float a[RPW];
#pragma unroll
    for (int it = 0; it < RPW; ++it) {
        const float4* e4 = (const float4*)(enc + (row0 + it) * H);
        a[it] = dot16(e4[lane], e4[lane + 64], e4[lane + 128], e4[lane + 192], vf);
    }

    // butterfly each row; full sum lands in ALL lanes
#pragma unroll
    for (int it = 0; it < RPW; ++it) {
#pragma unroll
        for (int off = 32; off > 0; off >>= 1)
            a[it] += __shfl_xor(a[it], off, 64);
    }
    if (lane == 0)
        *(float4*)(scores + row0) = make_float4(a[0], a[1], a[2], a[3]);

    // deferred wave softmax partial
    const float mw = fmaxf(fmaxf(a[0], a[1]), fmaxf(a[2], a[3]));
    float sw = __expf(a[0] - mw) + __expf(a[1] - mw) +
               __expf(a[2] - mw) + __expf(a[3] - mw);

    __shared__ float sm[4], ss[4];
    if (lane == 0) { sm[wv] = mw; ss[wv] = sw; }
    __syncthreads();
    if (tid == 0) {
        float m = sm[0], s = ss[0];
#pragma unroll
        for (int i = 1; i < 4; ++i) {
            const float nm = fmaxf(m, sm[i]);
            s = s * __expf(m - nm) + ss[i] * __expf(sm[i] - nm);
            m = nm;
        }
        pm[blk] = m; ps[blk] = s;
    }
}

// ---------------------------------------------------------------------------
// K3: every block redundantly combines the 2048 (m,s) pairs, then
// normalizes its 256 scores. grid 128 blocks x 256 threads.
// ---------------------------------------------------------------------------
__global__ __launch_bounds__(256) void finalize(const float* __restrict__ ws,
                                                float* __restrict__ out) {
    const float* scores = ws + WS_SCORES;
    const float* pm     = ws + WS_PM;
    const float* ps     = ws + WS_PS;

    const int tid  = threadIdx.x;
    const int lane = tid & 63;
    const int wv   = tid >> 6;

    float m = -INFINITY, s = 0.f;
#pragma unroll
    for (int i = 0; i < NB2 / 256; ++i) {
        const int idx = tid + i * 256;
        const float om = pm[idx], os = ps[idx];
        const float nm = fmaxf(m, om);
        s = s * __expf(m - nm) + os * __expf(om - nm);
        m = nm;
    }
#pragma unroll
    for (int off = 32; off > 0; off >>= 1) {
        const float om = __shfl_xor(m, off, 64);
        const float os = __shfl_xor(s, off, 64);
        const float nm = fmaxf(m, om);
        s = s * __expf(m - nm) + os * __expf(om - nm);
        m = nm;
    }
    __shared__ float sm[4], ss[4];
    if (lane == 0) { sm[wv] = m; ss[wv] = s; }
    __syncthreads();
    float M = sm[0], Ssum = ss[0];
#pragma unroll
    for (int i = 1; i < 4; ++i) {
        const float nm = fmaxf(M, sm[i]);
        Ssum = Ssum * __expf(M - nm) + ss[i] * __expf(sm[i] - nm);
        M = nm;
    }
    const float rs = 1.0f / Ssum;

    const int i = blockIdx.x * 256 + tid;
    out[i] = __expf(scores[i] - M) * rs;
}

extern "C" void kernel_launch(void* const* d_in, const int* in_sizes, int n_in,
                              void* d_out, int out_size, void* d_ws, size_t ws_size,
                              hipStream_t stream) {
    const float* hidden = (const float*)d_in[0];   // [H]
    const float* enc    = (const float*)d_in[1];   // [S, H]
    const float* W      = (const float*)d_in[2];   // [H, H]
    // d_in[3] = b — unused: b·hidden is a uniform softmax shift (cancels exactly).
    float* out = (float*)d_out;                    // [S] fp32
    float* ws  = (float*)d_ws;

    matvec_partial<<<dim3(16, 16), 256, 0, stream>>>(W, hidden, ws);
    reduce_v<<<4, 64, 0, stream>>>(ws);
    scores_partial<<<NB2, 256, 0, stream>>>(enc, ws);
    finalize<<<S / 256, 256, 0, stream>>>(ws, out);
}

// Round 4
// 201.277 us; speedup vs baseline: 1.5790x; 1.0140x over previous
//
#include <hip/hip_runtime.h>
#include <math.h>

#define H 1024
#define S 32768
#define NPART 16          // d-partials for the W^T @ hidden matvec
#define RPW 8             // rows per wave in K2
#define NB2 1024          // K2 blocks: S / (4 waves * RPW)

// ws layout (floats):
//   [0, 16384)        part[p][h]   p<16, h<1024
//   [16384, 17408)    pm[NB2]      per-block softmax max
//   [17408, 18432)    ps[NB2]      per-block softmax sumexp
//   [18432, 51200)    scores[S]
#define WS_PART   0
#define WS_PM     16384
#define WS_PS     17408
#define WS_SCORES 18432

// ---------------------------------------------------------------------------
// K1: part[by][h] = sum_{d in by-chunk of 64} W[d][h] * hidden[d]
// grid (16,16), block 256. One block per CU, perfectly coalesced W reads.
// ---------------------------------------------------------------------------
__global__ __launch_bounds__(256) void matvec_partial(const float* __restrict__ W,
                                                      const float* __restrict__ hidden,
                                                      float* __restrict__ ws) {
    float* part = ws + WS_PART;
    const int t  = threadIdx.x;
    const int l  = t & 63;
    const int dg = t >> 6;
    const int h  = blockIdx.x * 64 + l;
    const int d0 = blockIdx.y * 64 + dg * 16;

    float acc = 0.f;
#pragma unroll
    for (int i = 0; i < 16; ++i)
        acc += W[(size_t)(d0 + i) * H + h] * hidden[d0 + i];

    __shared__ float red[4][64];
    red[dg][l] = acc;
    __syncthreads();
    if (t < 64)
        part[blockIdx.y * H + blockIdx.x * 64 + l] =
            red[0][l] + red[1][l] + red[2][l] + red[3][l];
}

// ---------------------------------------------------------------------------
// K2: v-rebuild prologue (independent loads + tree sum, NOT a dependent
// chain) + scores + per-block softmax partials. 1024 blocks x 256 threads.
// First two enc rows are prefetched BEFORE the prologue so the dominant
// HBM stream starts immediately; the 64 KB partial read comes from L2.
// ---------------------------------------------------------------------------
__device__ __forceinline__ float4 add4(float4 a, float4 b) {
    return make_float4(a.x + b.x, a.y + b.y, a.z + b.z, a.w + b.w);
}

__device__ __forceinline__ float dot16(const float4 e0, const float4 e1,
                                       const float4 e2, const float4 e3,
                                       const float4 vf[4]) {
    float s0 = e0.x * vf[0].x + e0.y * vf[0].y + e0.z * vf[0].z + e0.w * vf[0].w;
    float s1 = e1.x * vf[1].x + e1.y * vf[1].y + e1.z * vf[1].z + e1.w * vf[1].w;
    float s2 = e2.x * vf[2].x + e2.y * vf[2].y + e2.z * vf[2].z + e2.w * vf[2].w;
    float s3 = e3.x * vf[3].x + e3.y * vf[3].y + e3.z * vf[3].z + e3.w * vf[3].w;
    return (s0 + s1) + (s2 + s3);
}

__global__ __launch_bounds__(256) void scores_partial(const float* __restrict__ enc,
                                                      float* __restrict__ ws) {
    float* scores = ws + WS_SCORES;
    float* pm     = ws + WS_PM;
    float* ps     = ws + WS_PS;
    const float* part = ws + WS_PART;

    const int tid  = threadIdx.x;
    const int lane = tid & 63;
    const int wv   = tid >> 6;
    const int blk  = blockIdx.x;
    const int gw   = blk * 4 + wv;                 // global wave id
    const size_t row0 = (size_t)gw * RPW;

    // --- prefetch first 2 enc rows: HBM stream starts before the prologue ---
    const float4* e4 = (const float4*)(enc + row0 * H);
    float4 p00 = e4[lane],       p01 = e4[lane + 64],
           p02 = e4[lane + 128], p03 = e4[lane + 192];
    float4 p10 = e4[256 + lane],       p11 = e4[256 + lane + 64],
           p12 = e4[256 + lane + 128], p13 = e4[256 + lane + 192];

    // --- v-rebuild prologue: 16 independent L2 loads, tree sum, LDS ---
    __shared__ float vsh[H];
    {
        const float4* p4 = (const float4*)part;
        float4 t[NPART];
#pragma unroll
        for (int p = 0; p < NPART; ++p) t[p] = p4[p * (H / 4) + tid];
#pragma unroll
        for (int p = 0; p < 8; ++p) t[p] = add4(t[p], t[p + 8]);
#pragma unroll
        for (int p = 0; p < 4; ++p) t[p] = add4(t[p], t[p + 4]);
        ((float4*)vsh)[tid] = add4(add4(t[0], t[2]), add4(t[1], t[3]));
    }
    __syncthreads();

    const float4* v4 = (const float4*)vsh;
    float4 vf[4];
#pragma unroll
    for (int k = 0; k < 4; ++k) vf[k] = v4[lane + 64 * k];

    float a[RPW];
    a[0] = dot16(p00, p01, p02, p03, vf);
    a[1] = dot16(p10, p11, p12, p13, vf);
#pragma unroll
    for (int it = 2; it < RPW; ++it) {
        const float4* r = e4 + it * 256;
        a[it] = dot16(r[lane], r[lane + 64], r[lane + 128], r[lane + 192], vf);
    }

    // butterfly each row; full row-sum lands in ALL lanes
#pragma unroll
    for (int it = 0; it < RPW; ++it) {
#pragma unroll
        for (int off = 32; off > 0; off >>= 1)
            a[it] += __shfl_xor(a[it], off, 64);
    }
    if (lane == 0) {
        *(float4*)(scores + row0)     = make_float4(a[0], a[1], a[2], a[3]);
        *(float4*)(scores + row0 + 4) = make_float4(a[4], a[5], a[6], a[7]);
    }

    // deferred wave softmax partial: fmax tree + independent exps
    float m01 = fmaxf(a[0], a[1]), m23 = fmaxf(a[2], a[3]);
    float m45 = fmaxf(a[4], a[5]), m67 = fmaxf(a[6], a[7]);
    const float mw = fmaxf(fmaxf(m01, m23), fmaxf(m45, m67));
    float sw = 0.f;
#pragma unroll
    for (int it = 0; it < RPW; ++it) sw += __expf(a[it] - mw);

    __shared__ float sm[4], ss[4];
    if (lane == 0) { sm[wv] = mw; ss[wv] = sw; }
    __syncthreads();
    if (tid == 0) {
        float m = sm[0], s = ss[0];
#pragma unroll
        for (int i = 1; i < 4; ++i) {
            const float nm = fmaxf(m, sm[i]);
            s = s * __expf(m - nm) + ss[i] * __expf(sm[i] - nm);
            m = nm;
        }
        pm[blk] = m; ps[blk] = s;
    }
}

// ---------------------------------------------------------------------------
// K3: every block redundantly combines the 1024 (m,s) pairs, then
// normalizes its 256 scores. grid 128 blocks x 256 threads.
// ---------------------------------------------------------------------------
__global__ __launch_bounds__(256) void finalize(const float* __restrict__ ws,
                                                float* __restrict__ out) {
    const float* scores = ws + WS_SCORES;
    const float* pm     = ws + WS_PM;
    const float* ps     = ws + WS_PS;

    const int tid  = threadIdx.x;
    const int lane = tid & 63;
    const int wv   = tid >> 6;

    float m = -INFINITY, s = 0.f;
#pragma unroll
    for (int i = 0; i < NB2 / 256; ++i) {
        const int idx = tid + i * 256;
        const float om = pm[idx], os = ps[idx];
        const float nm = fmaxf(m, om);
        s = s * __expf(m - nm) + os * __expf(om - nm);
        m = nm;
    }
#pragma unroll
    for (int off = 32; off > 0; off >>= 1) {
        const float om = __shfl_xor(m, off, 64);
        const float os = __shfl_xor(s, off, 64);
        const float nm = fmaxf(m, om);
        s = s * __expf(m - nm) + os * __expf(om - nm);
        m = nm;
    }
    __shared__ float sm[4], ss[4];
    if (lane == 0) { sm[wv] = m; ss[wv] = s; }
    __syncthreads();
    float M = sm[0], Ssum = ss[0];
#pragma unroll
    for (int i = 1; i < 4; ++i) {
        const float nm = fmaxf(M, sm[i]);
        Ssum = Ssum * __expf(M - nm) + ss[i] * __expf(sm[i] - nm);
        M = nm;
    }
    const float rs = 1.0f / Ssum;

    const int i = blockIdx.x * 256 + tid;
    out[i] = __expf(scores[i] - M) * rs;
}

extern "C" void kernel_launch(void* const* d_in, const int* in_sizes, int n_in,
                              void* d_out, int out_size, void* d_ws, size_t ws_size,
                              hipStream_t stream) {
    const float* hidden = (const float*)d_in[0];   // [H]
    const float* enc    = (const float*)d_in[1];   // [S, H]
    const float* W      = (const float*)d_in[2];   // [H, H]
    // d_in[3] = b — unused: b·hidden is a uniform softmax shift (cancels exactly).
    float* out = (float*)d_out;                    // [S] fp32
    float* ws  = (float*)d_ws;

    matvec_partial<<<dim3(16, 16), 256, 0, stream>>>(W, hidden, ws);
    scores_partial<<<NB2, 256, 0, stream>>>(enc, ws);
    finalize<<<S / 256, 256, 0, stream>>>(ws, out);
}